// Round 15
// baseline (254.577 us; speedup 1.0000x reference)
//
#include <hip/hip_runtime.h>
#include <hip/hip_bf16.h>

#define DH 128

static constexpr float TEMP_ = 10.0f;
static constexpr float LN_EPS_ = 1e-5f;

// ---------------- bf16 helpers ----------------
__device__ __forceinline__ unsigned short f2bf(float f) {
  union { float f; unsigned int i; } v; v.f = f;
  unsigned int b = v.i + 0x7FFFu + ((v.i >> 16) & 1u);   // RNE
  return (unsigned short)(b >> 16);
}
__device__ __forceinline__ void dec2(unsigned int u, float& lo, float& hi) {
  union { unsigned int i; float f; } a, b;
  a.i = u << 16; b.i = u & 0xFFFF0000u;
  lo = a.f; hi = b.f;
}
__device__ __forceinline__ void dec8(uint4 u, float* o) {
  dec2(u.x, o[0], o[1]); dec2(u.y, o[2], o[3]);
  dec2(u.z, o[4], o[5]); dec2(u.w, o[6], o[7]);
}
__device__ __forceinline__ unsigned int pack2(float lo, float hi) {
  return (unsigned int)f2bf(lo) | ((unsigned int)f2bf(hi) << 16);
}

__device__ __forceinline__ float grp_sum16(float v) {
  #pragma unroll
  for (int o = 8; o > 0; o >>= 1) v += __shfl_down(v, o, 16);
  return __shfl(v, 0, 16);
}

// ---------- fused: layer-1 GEMM (blocks < NT) + degree histogram ----------
__global__ __launch_bounds__(256) void k_gemm1_hist(const float* __restrict__ X,
                                                    const float* __restrict__ W,
                                                    unsigned short* __restrict__ Hb,
                                                    const int* __restrict__ ei, int E,
                                                    int* cnt_d, int* cnt_s, int NT) {
  __shared__ float Ws[64 * DH];
  __shared__ float xs[16 * 128];
  const int t = threadIdx.x;
  if ((int)blockIdx.x < NT) {
    const int row0 = blockIdx.x * 16;
    const float4* xg = (const float4*)(X + row0 * 128);
    float4* xs4 = (float4*)xs;
    xs4[t] = xg[t];
    xs4[t + 256] = xg[t + 256];
    const int c = t & 127, rg = t >> 7;   // RPT = 8
    float acc[8];
    #pragma unroll
    for (int r = 0; r < 8; ++r) acc[r] = 0.f;
    for (int kt = 0; kt < 2; ++kt) {
      __syncthreads();
      for (int i = t; i < 64 * DH; i += 256) Ws[i] = W[kt * 64 * DH + i];
      __syncthreads();
      for (int k = 0; k < 64; ++k) {
        float wv = Ws[k * DH + c];
        #pragma unroll
        for (int r = 0; r < 8; ++r)
          acc[r] += xs[(rg * 8 + r) * 128 + kt * 64 + k] * wv;
      }
    }
    #pragma unroll
    for (int r = 0; r < 8; ++r)
      Hb[(row0 + rg * 8 + r) * DH + c] = f2bf(acc[r]);
  } else {
    const int nb = gridDim.x - NT;
    for (int e = (blockIdx.x - NT) * 256 + t; e < E; e += nb * 256) {
      atomicAdd(&cnt_s[ei[e]], 1);
      atomicAdd(&cnt_d[ei[E + e]], 1);
    }
  }
}

// ---------- hierarchical scan A: 64 blocks (32/dir), ~250 nodes each ----------
__global__ __launch_bounds__(256) void k_scan_a(const int* __restrict__ cnt_d,
                                                const int* __restrict__ cnt_s,
                                                int* off_d, int* off_s, int* bsum,
                                                float* dinv, float* dego, int n) {
  __shared__ int ws4[4];
  const int t = threadIdx.x;
  const int dir = blockIdx.x >> 5, blk = blockIdx.x & 31;
  const int* cnt = dir ? cnt_s : cnt_d;
  int* off = dir ? off_s : off_d;
  const int NPB = (n + 31) >> 5;           // 250 for n=8000
  const int i = blk * NPB + t;
  const bool valid = (t < NPB) && (i < n);
  int tot = valid ? cnt[i] : 0;
  const int lane = t & 63, w = t >> 6;
  int v = tot;
  #pragma unroll
  for (int o = 1; o < 64; o <<= 1) {
    int u = __shfl_up(v, o, 64);
    if (lane >= o) v += u;
  }
  if (lane == 63) ws4[w] = v;
  __syncthreads();
  int wbase = 0;
  #pragma unroll
  for (int k = 0; k < 4; ++k) wbase += (k < w) ? ws4[k] : 0;
  const int excl = wbase + v - tot;
  if (valid) {
    off[i] = excl;                          // temp: block-local prefix
    if (dir == 0) dinv[i] = rsqrtf((float)tot + 1.0f);
    else          dego[i] = (float)tot;
  }
  if (t == 0) {
    int bt = 0;
    #pragma unroll
    for (int k = 0; k < 4; ++k) bt += ws4[k];
    bsum[dir * 32 + blk] = bt;
  }
}

// ---------- hierarchical scan B: finalize offsets, zero cnt (fill cursors) ----
__global__ __launch_bounds__(256) void k_scan_b(int* cnt_d, int* cnt_s,
                                                int* off_d, int* off_s,
                                                const int* __restrict__ bsum, int n) {
  __shared__ int sb;
  const int t = threadIdx.x;
  const int dir = blockIdx.x >> 5, blk = blockIdx.x & 31;
  int* cnt = dir ? cnt_s : cnt_d;
  int* off = dir ? off_s : off_d;
  if (t == 0) {
    int s = 0;
    for (int k = 0; k < blk; ++k) s += bsum[dir * 32 + k];
    sb = s;
  }
  __syncthreads();
  const int bbase = sb;
  const int NPB = (n + 31) >> 5;
  const int i = blk * NPB + t;
  if (t < NPB && i < n) {
    off[i] = bbase + off[i];
    cnt[i] = 0;
  }
  if (t == 1 && blk == 31) {
    int s = 0;
    for (int k = 0; k < 32; ++k) s += bsum[dir * 32 + k];
    off[n] = s;
  }
}

// ---------- degree counting sort -> assignment permutation (2 blocks) ----------
__global__ __launch_bounds__(1024) void k_sort(const int* __restrict__ off_d,
                                               const int* __restrict__ off_s,
                                               int* perm_d, int* perm_s, int n) {
  __shared__ int bins[1024];
  __shared__ int wsum[16];
  const int t = threadIdx.x;
  const int* off = blockIdx.x ? off_s : off_d;
  int* perm = blockIdx.x ? perm_s : perm_d;
  bins[t] = 0;
  __syncthreads();
  for (int i = t; i < n; i += 1024) {
    int d = off[i + 1] - off[i];
    atomicAdd(&bins[d < 1023 ? d : 1023], 1);
  }
  __syncthreads();
  int v = bins[t];
  const int lane = t & 63, w = t >> 6;
  int s = v;
  #pragma unroll
  for (int o = 1; o < 64; o <<= 1) {
    int u = __shfl_up(s, o, 64);
    if (lane >= o) s += u;
  }
  if (lane == 63) wsum[w] = s;
  __syncthreads();
  int base = 0;
  for (int k = 0; k < 16; ++k) base += (k < w) ? wsum[k] : 0;
  int excl = base + s - v;
  __syncthreads();
  bins[t] = excl;
  __syncthreads();
  for (int i = t; i < n; i += 1024) {
    int d = off[i + 1] - off[i];
    d = d < 1023 ? d : 1023;
    int pos = atomicAdd(&bins[d], 1);
    perm[pos] = i;
  }
}

__global__ void k_fill(const int* __restrict__ ei, int E,
                       const int* __restrict__ off_d, const int* __restrict__ off_s,
                       int* cnt_d, int* cnt_s, int* idx_d, int* idx_s) {
  int e = blockIdx.x * blockDim.x + threadIdx.x;
  if (e < E) {
    int s = ei[e], d = ei[E + e];
    int p = atomicAdd(&cnt_d[d], 1);
    idx_d[off_d[d] + p] = s;
    int q = atomicAdd(&cnt_s[s], 1);
    idx_s[off_s[s] + q] = d;
  }
}

// ------- conv aggregate: 128-thread blocks, 8 nodes (deg-sorted) -----------
__global__ __launch_bounds__(128) void k_conv_agg(const unsigned short* __restrict__ Hb,
                                                  const float* __restrict__ dinv,
                                                  const float* __restrict__ b,
                                                  const int* __restrict__ off_d,
                                                  const int* __restrict__ idx_d,
                                                  const int* __restrict__ perm,
                                                  float* __restrict__ G,
                                                  unsigned short* __restrict__ Gb,
                                                  float* __restrict__ sq) {
  const int lane = threadIdx.x & 15;
  const int i = perm[blockIdx.x * 8 + (threadIdx.x >> 4)];
  const uint4* Hv = (const uint4*)Hb;
  const float di = dinv[i];
  float acc[8];
  {
    float t8[8]; dec8(Hv[i * 16 + lane], t8);
    #pragma unroll
    for (int k = 0; k < 8; ++k) acc[k] = di * t8[k];   // self loop
  }
  int o = off_d[i];
  const int oe = off_d[i + 1];
  for (; o + 8 <= oe; o += 8) {
    int s[8]; float dv[8]; uint4 r[8];
    #pragma unroll
    for (int j = 0; j < 8; ++j) s[j] = idx_d[o + j];
    #pragma unroll
    for (int j = 0; j < 8; ++j) { r[j] = Hv[s[j] * 16 + lane]; dv[j] = dinv[s[j]]; }
    #pragma unroll
    for (int j = 0; j < 8; ++j) {
      float t8[8]; dec8(r[j], t8);
      #pragma unroll
      for (int k = 0; k < 8; ++k) acc[k] = fmaf(dv[j], t8[k], acc[k]);
    }
  }
  for (; o < oe; ++o) {
    int s = idx_d[o];
    float dvs = dinv[s];
    float t8[8]; dec8(Hv[s * 16 + lane], t8);
    #pragma unroll
    for (int k = 0; k < 8; ++k) acc[k] = fmaf(dvs, t8[k], acc[k]);
  }
  const float4 b0 = ((const float4*)b)[lane * 2];
  const float4 b1 = ((const float4*)b)[lane * 2 + 1];
  float gi[8];
  gi[0] = fmaf(di, acc[0], b0.x); gi[1] = fmaf(di, acc[1], b0.y);
  gi[2] = fmaf(di, acc[2], b0.z); gi[3] = fmaf(di, acc[3], b0.w);
  gi[4] = fmaf(di, acc[4], b1.x); gi[5] = fmaf(di, acc[5], b1.y);
  gi[6] = fmaf(di, acc[6], b1.z); gi[7] = fmaf(di, acc[7], b1.w);
  ((float4*)G)[i * 32 + lane * 2]     = make_float4(gi[0], gi[1], gi[2], gi[3]);
  ((float4*)G)[i * 32 + lane * 2 + 1] = make_float4(gi[4], gi[5], gi[6], gi[7]);
  uint4 gp;
  gp.x = pack2(gi[0], gi[1]); gp.y = pack2(gi[2], gi[3]);
  gp.z = pack2(gi[4], gi[5]); gp.w = pack2(gi[6], gi[7]);
  ((uint4*)Gb)[i * 16 + lane] = gp;
  float s2 = 0.f;
  #pragma unroll
  for (int k = 0; k < 8; ++k) s2 += gi[k] * gi[k];
  s2 = grp_sum16(s2);
  if (lane == 0) sq[i] = s2;
}

// ------- Ax = A@G (CSR_src), Asq, En: 128-thread blocks (deg-sorted) -------
__global__ __launch_bounds__(128) void k_ax_en(const float* __restrict__ G,
                                               const unsigned short* __restrict__ Gb,
                                               const float* __restrict__ sq,
                                               const float* __restrict__ dego,
                                               const int* __restrict__ off_s,
                                               const int* __restrict__ idx_s,
                                               const int* __restrict__ perm,
                                               float* __restrict__ Ax,
                                               float* __restrict__ En) {
  const int lane = threadIdx.x & 15;
  const int i = perm[blockIdx.x * 8 + (threadIdx.x >> 4)];
  const uint4* Gv = (const uint4*)Gb;
  float axf[8];
  #pragma unroll
  for (int k = 0; k < 8; ++k) axf[k] = 0.f;
  float asq = 0.f;
  int o = off_s[i];
  const int oe = off_s[i + 1];
  for (; o + 8 <= oe; o += 8) {
    int s[8]; float qv[8]; uint4 r[8];
    #pragma unroll
    for (int j = 0; j < 8; ++j) s[j] = idx_s[o + j];
    #pragma unroll
    for (int j = 0; j < 8; ++j) { r[j] = Gv[s[j] * 16 + lane]; qv[j] = sq[s[j]]; }
    #pragma unroll
    for (int j = 0; j < 8; ++j) {
      float t8[8]; dec8(r[j], t8);
      asq += qv[j];
      #pragma unroll
      for (int k = 0; k < 8; ++k) axf[k] += t8[k];
    }
  }
  for (; o < oe; ++o) {
    int s = idx_s[o];
    float t8[8]; dec8(Gv[s * 16 + lane], t8);
    asq += sq[s];
    #pragma unroll
    for (int k = 0; k < 8; ++k) axf[k] += t8[k];
  }
  ((float4*)Ax)[i * 32 + lane * 2]     = make_float4(axf[0], axf[1], axf[2], axf[3]);
  ((float4*)Ax)[i * 32 + lane * 2 + 1] = make_float4(axf[4], axf[5], axf[6], axf[7]);
  const float4 g0 = ((const float4*)G)[i * 32 + lane * 2];
  const float4 g1 = ((const float4*)G)[i * 32 + lane * 2 + 1];
  float dot = g0.x * axf[0] + g0.y * axf[1] + g0.z * axf[2] + g0.w * axf[3]
            + g1.x * axf[4] + g1.y * axf[5] + g1.z * axf[6] + g1.w * axf[7];
  dot = grp_sum16(dot);
  if (lane == 0) En[i] = 0.5f * (dego[i] * sq[i] + asq - 2.f * dot);
}

// ---------------- softmax over entropies -> c (single block) ---------------
__device__ __forceinline__ float red1024(float v, bool domax, float* sm) {
  #pragma unroll
  for (int o = 32; o > 0; o >>= 1) {
    float u = __shfl_down(v, o, 64);
    v = domax ? fmaxf(v, u) : v + u;
  }
  if ((threadIdx.x & 63) == 0) sm[threadIdx.x >> 6] = v;
  __syncthreads();
  if (threadIdx.x == 0) {
    float r = sm[0];
    for (int k = 1; k < 16; ++k) r = domax ? fmaxf(r, sm[k]) : r + sm[k];
    sm[0] = r;
  }
  __syncthreads();
  float r = sm[0];
  __syncthreads();
  return r;
}

__global__ __launch_bounds__(1024) void k_softc(const float* __restrict__ En,
                                                float* __restrict__ c, int n) {
  __shared__ float sm[16];
  const int t = threadIdx.x;
  float m = -1e30f;
  for (int i = t; i < n; i += 1024) m = fmaxf(m, En[i]);
  m = red1024(m, true, sm);
  const float invden = -1.0f / ((m + 1e-12f) * TEMP_);
  float se = 0.f, sl = 0.f;
  for (int i = t; i < n; i += 1024) {
    float li = En[i] * invden;
    float e = __expf(li);
    se += e; sl += e * li;
  }
  se = red1024(se, false, sm);
  sl = red1024(sl, false, sm);
  const float logZ = __logf(se);
  const float S = logZ - sl / se;
  const float cmul = (1.0f / se) * (1.0f / TEMP_);
  const float cadd = S - logZ;
  for (int i = t; i < n; i += 1024) {
    float li = En[i] * invden;
    c[i] = __expf(li) * cmul * (li + cadd);
  }
}

// ------- fused: combine (cv global) + relu + LN + GEMM tile (deg-sorted) ----
template <int DOUT>
__global__ __launch_bounds__(256) void k_combine_gemm(const float* __restrict__ G,
                                                      const unsigned short* __restrict__ Gb,
                                                      const float* __restrict__ Ax,
                                                      const float* __restrict__ cv,
                                                      const float* __restrict__ dego,
                                                      const int* __restrict__ off_d,
                                                      const int* __restrict__ idx_d,
                                                      const int* __restrict__ perm,
                                                      const float* __restrict__ gamma,
                                                      const float* __restrict__ beta,
                                                      const float* __restrict__ W,
                                                      unsigned short* __restrict__ Hb) {
  __shared__ float Ws[32 * DOUT];        // 32-row k-tile of W
  __shared__ float xs[16 * 128];
  __shared__ int nid[16];
  const int t = threadIdx.x;
  if (t < 16) nid[t] = perm[blockIdx.x * 16 + t];
  __syncthreads();
  const int lane = t & 15;
  const int i = nid[t >> 4];
  const uint4* Gv = (const uint4*)Gb;
  const float4 g0 = ((const float4*)G)[i * 32 + lane * 2];
  const float4 g1 = ((const float4*)G)[i * 32 + lane * 2 + 1];
  const float gi[8] = { g0.x, g0.y, g0.z, g0.w, g1.x, g1.y, g1.z, g1.w };
  float tf[8];
  #pragma unroll
  for (int k = 0; k < 8; ++k) tf[k] = 0.f;
  float atc = 0.f;
  int o = off_d[i];
  const int oe = off_d[i + 1];
  for (; o + 8 <= oe; o += 8) {
    int s[8]; float cs[8]; uint4 r[8];
    #pragma unroll
    for (int j = 0; j < 8; ++j) s[j] = idx_d[o + j];
    #pragma unroll
    for (int j = 0; j < 8; ++j) { r[j] = Gv[s[j] * 16 + lane]; cs[j] = cv[s[j]]; }
    #pragma unroll
    for (int j = 0; j < 8; ++j) {
      atc += cs[j];
      float t8[8]; dec8(r[j], t8);
      #pragma unroll
      for (int k = 0; k < 8; ++k) tf[k] = fmaf(cs[j], t8[k], tf[k]);
    }
  }
  for (; o < oe; ++o) {
    int s = idx_d[o];
    float cs = cv[s];
    atc += cs;
    float t8[8]; dec8(Gv[s * 16 + lane], t8);
    #pragma unroll
    for (int k = 0; k < 8; ++k) tf[k] = fmaf(cs, t8[k], tf[k]);
  }
  const float ci = cv[i];
  const float dg = dego[i];
  const float4 a0 = ((const float4*)Ax)[i * 32 + lane * 2];
  const float4 a1 = ((const float4*)Ax)[i * 32 + lane * 2 + 1];
  const float axi[8] = { a0.x, a0.y, a0.z, a0.w, a1.x, a1.y, a1.z, a1.w };
  float v[8];
  float ssum = 0.f;
  #pragma unroll
  for (int k = 0; k < 8; ++k) {
    v[k] = fmaxf(gi[k] + ci * (dg * gi[k] - axi[k]) + atc * gi[k] - tf[k], 0.f);
    ssum += v[k];
  }
  float mu = grp_sum16(ssum) * (1.f / 128.f);
  float vsum = 0.f;
  #pragma unroll
  for (int k = 0; k < 8; ++k) {
    v[k] -= mu;
    vsum += v[k] * v[k];
  }
  float var = grp_sum16(vsum) * (1.f / 128.f);
  float rs = rsqrtf(var + LN_EPS_);
  const float4 ga0 = ((const float4*)gamma)[lane * 2];
  const float4 ga1 = ((const float4*)gamma)[lane * 2 + 1];
  const float4 be0 = ((const float4*)beta)[lane * 2];
  const float4 be1 = ((const float4*)beta)[lane * 2 + 1];
  float4 o0, o1;
  o0.x = fmaf(v[0] * rs, ga0.x, be0.x); o0.y = fmaf(v[1] * rs, ga0.y, be0.y);
  o0.z = fmaf(v[2] * rs, ga0.z, be0.z); o0.w = fmaf(v[3] * rs, ga0.w, be0.w);
  o1.x = fmaf(v[4] * rs, ga1.x, be1.x); o1.y = fmaf(v[5] * rs, ga1.y, be1.y);
  o1.z = fmaf(v[6] * rs, ga1.z, be1.z); o1.w = fmaf(v[7] * rs, ga1.w, be1.w);

  // ---- stage LN rows to LDS, then GEMM this 16-row tile ----
  float* xrow = xs + (t >> 4) * 128 + lane * 8;
  ((float4*)xrow)[0] = o0;
  ((float4*)xrow)[1] = o1;

  constexpr int RPT = (16 * DOUT) / 256;
  const int c = t % DOUT;
  const int rg = t / DOUT;
  float acc[RPT];
  #pragma unroll
  for (int r = 0; r < RPT; ++r) acc[r] = 0.f;
  for (int kt = 0; kt < 4; ++kt) {
    if (kt) __syncthreads();
    for (int idx = t; idx < 32 * DOUT; idx += 256) Ws[idx] = W[kt * 32 * DOUT + idx];
    __syncthreads();
    for (int k = 0; k < 32; ++k) {
      float wv = Ws[k * DOUT + c];
      #pragma unroll
      for (int r = 0; r < RPT; ++r)
        acc[r] += xs[(rg * RPT + r) * 128 + kt * 32 + k] * wv;
    }
  }
  #pragma unroll
  for (int r = 0; r < RPT; ++r)
    Hb[nid[rg * RPT + r] * DOUT + c] = f2bf(acc[r]);
}

// ------- final conv aggregate: 128-thread blocks, 16 nodes (deg-sorted) ----
__global__ __launch_bounds__(128) void k_final_agg(const unsigned short* __restrict__ Hb,
                                                   const float* __restrict__ dinv,
                                                   const float* __restrict__ bout,
                                                   const int* __restrict__ off_d,
                                                   const int* __restrict__ idx_d,
                                                   const int* __restrict__ perm,
                                                   float* __restrict__ out) {
  const int lane = threadIdx.x & 7;
  const int i = perm[blockIdx.x * 16 + (threadIdx.x >> 3)];
  const uint4* Hv = (const uint4*)Hb;
  const float di = dinv[i];
  float acc[8];
  {
    float t8[8]; dec8(Hv[i * 8 + lane], t8);
    #pragma unroll
    for (int k = 0; k < 8; ++k) acc[k] = di * t8[k];
  }
  int o = off_d[i];
  const int oe = off_d[i + 1];
  for (; o + 8 <= oe; o += 8) {
    int s[8]; float dv[8]; uint4 r[8];
    #pragma unroll
    for (int j = 0; j < 8; ++j) s[j] = idx_d[o + j];
    #pragma unroll
    for (int j = 0; j < 8; ++j) { r[j] = Hv[s[j] * 8 + lane]; dv[j] = dinv[s[j]]; }
    #pragma unroll
    for (int j = 0; j < 8; ++j) {
      float t8[8]; dec8(r[j], t8);
      #pragma unroll
      for (int k = 0; k < 8; ++k) acc[k] = fmaf(dv[j], t8[k], acc[k]);
    }
  }
  for (; o < oe; ++o) {
    int s = idx_d[o];
    float dvs = dinv[s];
    float t8[8]; dec8(Hv[s * 8 + lane], t8);
    #pragma unroll
    for (int k = 0; k < 8; ++k) acc[k] = fmaf(dvs, t8[k], acc[k]);
  }
  const float4 b0 = ((const float4*)bout)[lane * 2];
  const float4 b1 = ((const float4*)bout)[lane * 2 + 1];
  float4 r0, r1;
  r0.x = fmaf(di, acc[0], b0.x); r0.y = fmaf(di, acc[1], b0.y);
  r0.z = fmaf(di, acc[2], b0.z); r0.w = fmaf(di, acc[3], b0.w);
  r1.x = fmaf(di, acc[4], b1.x); r1.y = fmaf(di, acc[5], b1.y);
  r1.z = fmaf(di, acc[6], b1.z); r1.w = fmaf(di, acc[7], b1.w);
  ((float4*)out)[i * 16 + lane * 2]     = r0;
  ((float4*)out)[i * 16 + lane * 2 + 1] = r1;
}

extern "C" void kernel_launch(void* const* d_in, const int* in_sizes, int n_in,
                              void* d_out, int out_size, void* d_ws, size_t ws_size,
                              hipStream_t stream) {
  const float* x    = (const float*)d_in[0];
  const int*   ei   = (const int*)d_in[1];
  const float* W1   = (const float*)d_in[2];
  const float* b1   = (const float*)d_in[3];
  const float* W2   = (const float*)d_in[4];
  const float* b2   = (const float*)d_in[5];
  const float* Wout = (const float*)d_in[6];
  const float* bout = (const float*)d_in[7];
  const float* gam  = (const float*)d_in[8];
  const float* bet  = (const float*)d_in[9];
  float* out = (float*)d_out;

  const int N = in_sizes[0] / DH;   // 8000
  const int E = in_sizes[1] / 2;    // 256000

  float* ws = (float*)d_ws;
  float* G  = ws;   ws += N * DH;
  float* Ax = ws;   ws += N * DH;
  float* sq = ws;   ws += N;
  float* En = ws;   ws += N;
  float* cv = ws;   ws += N;
  float* dinv = ws; ws += N;
  float* dego = ws; ws += N;
  unsigned short* Hb = (unsigned short*)ws; ws += N * DH / 2;   // bf16 N x 128
  unsigned short* Gb = (unsigned short*)ws; ws += N * DH / 2;   // bf16 N x 128
  int* cnt_d  = (int*)ws; ws += N;
  int* cnt_s  = (int*)ws; ws += N;
  int* off_d  = (int*)ws; ws += N + 4;
  int* off_s  = (int*)ws; ws += N + 4;
  int* perm_d = (int*)ws; ws += N;
  int* perm_s = (int*)ws; ws += N;
  int* bsum   = (int*)ws; ws += 64;
  int* idx_d  = (int*)ws; ws += E;
  int* idx_s  = (int*)ws; ws += E;

  const int NT = N / 16;            // 500 gemm tile blocks

  hipMemsetAsync(cnt_d, 0, 2 * N * sizeof(int), stream);  // cnt_d, cnt_s
  k_gemm1_hist<<<NT + 256, 256, 0, stream>>>(x, W1, Hb, ei, E, cnt_d, cnt_s, NT);
  k_scan_a<<<64, 256, 0, stream>>>(cnt_d, cnt_s, off_d, off_s, bsum, dinv, dego, N);
  k_scan_b<<<64, 256, 0, stream>>>(cnt_d, cnt_s, off_d, off_s, bsum, N);
  k_sort<<<2, 1024, 0, stream>>>(off_d, off_s, perm_d, perm_s, N);
  k_fill<<<(E + 255) / 256, 256, 0, stream>>>(ei, E, off_d, off_s, cnt_d, cnt_s,
                                              idx_d, idx_s);

  // layer 0
  k_conv_agg<<<N / 8, 128, 0, stream>>>(Hb, dinv, b1, off_d, idx_d, perm_d,
                                        G, Gb, sq);
  k_ax_en<<<N / 8, 128, 0, stream>>>(G, Gb, sq, dego, off_s, idx_s, perm_s,
                                     Ax, En);
  k_softc<<<1, 1024, 0, stream>>>(En, cv, N);
  k_combine_gemm<128><<<N / 16, 256, 0, stream>>>(G, Gb, Ax, cv, dego, off_d,
                                                  idx_d, perm_d, gam, bet, W2, Hb);
  // layer 1
  k_conv_agg<<<N / 8, 128, 0, stream>>>(Hb, dinv, b2, off_d, idx_d, perm_d,
                                        G, Gb, sq);
  k_ax_en<<<N / 8, 128, 0, stream>>>(G, Gb, sq, dego, off_s, idx_s, perm_s,
                                     Ax, En);
  k_softc<<<1, 1024, 0, stream>>>(En, cv, N);
  k_combine_gemm<64><<<N / 16, 256, 0, stream>>>(G, Gb, Ax, cv, dego, off_d,
                                                 idx_d, perm_d, gam, bet, Wout, Hb);
  k_final_agg<<<N / 16, 128, 0, stream>>>(Hb, dinv, bout, off_d, idx_d, perm_d, out);
}

// Round 16
// 236.774 us; speedup vs baseline: 1.0752x; 1.0752x over previous
//
#include <hip/hip_runtime.h>
#include <hip/hip_bf16.h>

#define DH 128

static constexpr float TEMP_ = 10.0f;
static constexpr float LN_EPS_ = 1e-5f;

// ---------------- bf16 helpers ----------------
__device__ __forceinline__ unsigned short f2bf(float f) {
  union { float f; unsigned int i; } v; v.f = f;
  unsigned int b = v.i + 0x7FFFu + ((v.i >> 16) & 1u);   // RNE
  return (unsigned short)(b >> 16);
}
__device__ __forceinline__ void dec2(unsigned int u, float& lo, float& hi) {
  union { unsigned int i; float f; } a, b;
  a.i = u << 16; b.i = u & 0xFFFF0000u;
  lo = a.f; hi = b.f;
}
__device__ __forceinline__ void dec8(uint4 u, float* o) {
  dec2(u.x, o[0], o[1]); dec2(u.y, o[2], o[3]);
  dec2(u.z, o[4], o[5]); dec2(u.w, o[6], o[7]);
}
__device__ __forceinline__ unsigned int pack2(float lo, float hi) {
  return (unsigned int)f2bf(lo) | ((unsigned int)f2bf(hi) << 16);
}

__device__ __forceinline__ float grp_sum16(float v) {
  #pragma unroll
  for (int o = 8; o > 0; o >>= 1) v += __shfl_down(v, o, 16);
  return __shfl(v, 0, 16);
}

// 256-thread block reduce; s4 = 4-float LDS scratch. Returns to all threads.
__device__ __forceinline__ float blkred(float v, bool mx, float* s4) {
  const int t = threadIdx.x;
  #pragma unroll
  for (int o = 32; o > 0; o >>= 1) {
    float u = __shfl_down(v, o, 64);
    v = mx ? fmaxf(v, u) : v + u;
  }
  __syncthreads();
  if ((t & 63) == 0) s4[t >> 6] = v;
  __syncthreads();
  float r = mx ? fmaxf(fmaxf(s4[0], s4[1]), fmaxf(s4[2], s4[3]))
               : (s4[0] + s4[1]) + (s4[2] + s4[3]);
  __syncthreads();
  return r;
}

// ---------------- degree histogram ----------------
__global__ void k_hist(const int* __restrict__ ei, int E, int* cnt_d, int* cnt_s) {
  for (int e = blockIdx.x * 256 + threadIdx.x; e < E; e += gridDim.x * 256) {
    atomicAdd(&cnt_s[ei[e]], 1);
    atomicAdd(&cnt_d[ei[E + e]], 1);
  }
}

// ---------- hierarchical scan A: 64 blocks (32/dir), ~250 nodes each ----------
__global__ __launch_bounds__(256) void k_scan_a(const int* __restrict__ cnt_d,
                                                const int* __restrict__ cnt_s,
                                                int* off_d, int* off_s, int* bsum,
                                                float* dinv, float* dego, int n) {
  __shared__ int ws4[4];
  const int t = threadIdx.x;
  const int dir = blockIdx.x >> 5, blk = blockIdx.x & 31;
  const int* cnt = dir ? cnt_s : cnt_d;
  int* off = dir ? off_s : off_d;
  const int NPB = (n + 31) >> 5;           // 250 for n=8000
  const int i = blk * NPB + t;
  const bool valid = (t < NPB) && (i < n);
  int tot = valid ? cnt[i] : 0;
  const int lane = t & 63, w = t >> 6;
  int v = tot;
  #pragma unroll
  for (int o = 1; o < 64; o <<= 1) {
    int u = __shfl_up(v, o, 64);
    if (lane >= o) v += u;
  }
  if (lane == 63) ws4[w] = v;
  __syncthreads();
  int wbase = 0;
  #pragma unroll
  for (int k = 0; k < 4; ++k) wbase += (k < w) ? ws4[k] : 0;
  const int excl = wbase + v - tot;
  if (valid) {
    off[i] = excl;                          // temp: block-local prefix
    if (dir == 0) dinv[i] = rsqrtf((float)tot + 1.0f);
    else          dego[i] = (float)tot;
  }
  if (t == 0) {
    int bt = 0;
    #pragma unroll
    for (int k = 0; k < 4; ++k) bt += ws4[k];
    bsum[dir * 32 + blk] = bt;
  }
}

// ---------- hierarchical scan B: finalize offsets, zero cnt (fill cursors) ----
__global__ __launch_bounds__(256) void k_scan_b(int* cnt_d, int* cnt_s,
                                                int* off_d, int* off_s,
                                                const int* __restrict__ bsum, int n) {
  __shared__ int sb;
  const int t = threadIdx.x;
  const int dir = blockIdx.x >> 5, blk = blockIdx.x & 31;
  int* cnt = dir ? cnt_s : cnt_d;
  int* off = dir ? off_s : off_d;
  if (t == 0) {
    int s = 0;
    for (int k = 0; k < blk; ++k) s += bsum[dir * 32 + k];
    sb = s;
  }
  __syncthreads();
  const int bbase = sb;
  const int NPB = (n + 31) >> 5;
  const int i = blk * NPB + t;
  if (t < NPB && i < n) {
    off[i] = bbase + off[i];
    cnt[i] = 0;
  }
  if (t == 1 && blk == 31) {
    int s = 0;
    for (int k = 0; k < 32; ++k) s += bsum[dir * 32 + k];
    off[n] = s;
  }
}

// ---- fused: layer-1 GEMM with dinv prescale (blocks < NT) + CSR fill ------
// Hbs[i] = dinv[i] * (X @ W1)[i]  (bf16)
__global__ __launch_bounds__(256) void k_gemm1_fill(const float* __restrict__ X,
                                                    const float* __restrict__ W,
                                                    const float* __restrict__ dinv,
                                                    unsigned short* __restrict__ Hb,
                                                    const int* __restrict__ ei, int E,
                                                    const int* __restrict__ off_d,
                                                    const int* __restrict__ off_s,
                                                    int* cnt_d, int* cnt_s,
                                                    int* idx_d, int* idx_s, int NT) {
  __shared__ float Ws[64 * DH];
  __shared__ float xs[16 * 128];
  const int t = threadIdx.x;
  if ((int)blockIdx.x < NT) {
    const int row0 = blockIdx.x * 16;
    const float4* xg = (const float4*)(X + row0 * 128);
    float4* xs4 = (float4*)xs;
    xs4[t] = xg[t];
    xs4[t + 256] = xg[t + 256];
    const int c = t & 127, rg = t >> 7;   // RPT = 8
    float acc[8];
    #pragma unroll
    for (int r = 0; r < 8; ++r) acc[r] = 0.f;
    for (int kt = 0; kt < 2; ++kt) {
      __syncthreads();
      for (int i = t; i < 64 * DH; i += 256) Ws[i] = W[kt * 64 * DH + i];
      __syncthreads();
      for (int k = 0; k < 64; ++k) {
        float wv = Ws[k * DH + c];
        #pragma unroll
        for (int r = 0; r < 8; ++r)
          acc[r] += xs[(rg * 8 + r) * 128 + kt * 64 + k] * wv;
      }
    }
    #pragma unroll
    for (int r = 0; r < 8; ++r) {
      const int row = row0 + rg * 8 + r;
      Hb[row * DH + c] = f2bf(dinv[row] * acc[r]);
    }
  } else {
    const int nb = gridDim.x - NT;
    for (int e = (blockIdx.x - NT) * 256 + t; e < E; e += nb * 256) {
      int s = ei[e], d = ei[E + e];
      int p = atomicAdd(&cnt_d[d], 1);
      idx_d[off_d[d] + p] = s;
      int q = atomicAdd(&cnt_s[s], 1);
      idx_s[off_s[s] + q] = d;
    }
  }
}

// ------- conv aggregate (prescaled rows): 16 lanes/node, uint4/lane --------
// G_i = b + dinv_i * (Hbs[i] + sum_{s in in(i)} Hbs[s])
__global__ __launch_bounds__(256) void k_conv_agg(const unsigned short* __restrict__ Hb,
                                                  const float* __restrict__ dinv,
                                                  const float* __restrict__ b,
                                                  const int* __restrict__ off_d,
                                                  const int* __restrict__ idx_d,
                                                  float* __restrict__ G,
                                                  unsigned short* __restrict__ Gb,
                                                  float* __restrict__ sq) {
  const int lane = threadIdx.x & 15;
  const int i = blockIdx.x * 16 + (threadIdx.x >> 4);
  const uint4* Hv = (const uint4*)Hb;
  const float di = dinv[i];
  float acc[8];
  dec8(Hv[i * 16 + lane], acc);              // self row (already dinv-scaled)
  int o = off_d[i];
  const int oe = off_d[i + 1];
  for (; o + 8 <= oe; o += 8) {
    int s[8]; uint4 r[8];
    #pragma unroll
    for (int j = 0; j < 8; ++j) s[j] = idx_d[o + j];
    #pragma unroll
    for (int j = 0; j < 8; ++j) r[j] = Hv[s[j] * 16 + lane];
    #pragma unroll
    for (int j = 0; j < 8; ++j) {
      float t8[8]; dec8(r[j], t8);
      #pragma unroll
      for (int k = 0; k < 8; ++k) acc[k] += t8[k];
    }
  }
  for (; o < oe; ++o) {
    int s = idx_d[o];
    float t8[8]; dec8(Hv[s * 16 + lane], t8);
    #pragma unroll
    for (int k = 0; k < 8; ++k) acc[k] += t8[k];
  }
  const float4 b0 = ((const float4*)b)[lane * 2];
  const float4 b1 = ((const float4*)b)[lane * 2 + 1];
  float gi[8];
  gi[0] = fmaf(di, acc[0], b0.x); gi[1] = fmaf(di, acc[1], b0.y);
  gi[2] = fmaf(di, acc[2], b0.z); gi[3] = fmaf(di, acc[3], b0.w);
  gi[4] = fmaf(di, acc[4], b1.x); gi[5] = fmaf(di, acc[5], b1.y);
  gi[6] = fmaf(di, acc[6], b1.z); gi[7] = fmaf(di, acc[7], b1.w);
  ((float4*)G)[i * 32 + lane * 2]     = make_float4(gi[0], gi[1], gi[2], gi[3]);
  ((float4*)G)[i * 32 + lane * 2 + 1] = make_float4(gi[4], gi[5], gi[6], gi[7]);
  uint4 gp;
  gp.x = pack2(gi[0], gi[1]); gp.y = pack2(gi[2], gi[3]);
  gp.z = pack2(gi[4], gi[5]); gp.w = pack2(gi[6], gi[7]);
  ((uint4*)Gb)[i * 16 + lane] = gp;
  float s2 = 0.f;
  #pragma unroll
  for (int k = 0; k < 8; ++k) s2 += gi[k] * gi[k];
  s2 = grp_sum16(s2);
  if (lane == 0) sq[i] = s2;
}

// ------- Ax = A@G (CSR_src), Asq, En -------------------------------------
__global__ __launch_bounds__(256) void k_ax_en(const float* __restrict__ G,
                                               const unsigned short* __restrict__ Gb,
                                               const float* __restrict__ sq,
                                               const float* __restrict__ dego,
                                               const int* __restrict__ off_s,
                                               const int* __restrict__ idx_s,
                                               float* __restrict__ Ax,
                                               float* __restrict__ En) {
  const int lane = threadIdx.x & 15;
  const int i = blockIdx.x * 16 + (threadIdx.x >> 4);
  const uint4* Gv = (const uint4*)Gb;
  float axf[8];
  #pragma unroll
  for (int k = 0; k < 8; ++k) axf[k] = 0.f;
  float asq = 0.f;
  int o = off_s[i];
  const int oe = off_s[i + 1];
  for (; o + 8 <= oe; o += 8) {
    int s[8]; float qv[8]; uint4 r[8];
    #pragma unroll
    for (int j = 0; j < 8; ++j) s[j] = idx_s[o + j];
    #pragma unroll
    for (int j = 0; j < 8; ++j) { r[j] = Gv[s[j] * 16 + lane]; qv[j] = sq[s[j]]; }
    #pragma unroll
    for (int j = 0; j < 8; ++j) {
      float t8[8]; dec8(r[j], t8);
      asq += qv[j];
      #pragma unroll
      for (int k = 0; k < 8; ++k) axf[k] += t8[k];
    }
  }
  for (; o < oe; ++o) {
    int s = idx_s[o];
    float t8[8]; dec8(Gv[s * 16 + lane], t8);
    asq += sq[s];
    #pragma unroll
    for (int k = 0; k < 8; ++k) axf[k] += t8[k];
  }
  ((float4*)Ax)[i * 32 + lane * 2]     = make_float4(axf[0], axf[1], axf[2], axf[3]);
  ((float4*)Ax)[i * 32 + lane * 2 + 1] = make_float4(axf[4], axf[5], axf[6], axf[7]);
  const float4 g0 = ((const float4*)G)[i * 32 + lane * 2];
  const float4 g1 = ((const float4*)G)[i * 32 + lane * 2 + 1];
  float dot = g0.x * axf[0] + g0.y * axf[1] + g0.z * axf[2] + g0.w * axf[3]
            + g1.x * axf[4] + g1.y * axf[5] + g1.z * axf[6] + g1.w * axf[7];
  dot = grp_sum16(dot);
  if (lane == 0) En[i] = 0.5f * (dego[i] * sq[i] + asq - 2.f * dot);
}

// ------- fused: softmax stats + combine + relu + LN + GEMM tile ------------
// Block = 16 nodes (16 lanes x 8 feats each) = one 16-row GEMM tile.
// Writes Hbs[n,DOUT] (bf16) = dinv .* (LN_out[n,128] @ W[128,DOUT]).
template <int DOUT>
__global__ __launch_bounds__(256) void k_combine_gemm(const float* __restrict__ G,
                                                      const unsigned short* __restrict__ Gb,
                                                      const float* __restrict__ Ax,
                                                      const float* __restrict__ En,
                                                      const float* __restrict__ dego,
                                                      const float* __restrict__ dinv,
                                                      const int* __restrict__ off_d,
                                                      const int* __restrict__ idx_d,
                                                      const float* __restrict__ gamma,
                                                      const float* __restrict__ beta,
                                                      const float* __restrict__ W,
                                                      unsigned short* __restrict__ Hb,
                                                      int n) {
  __shared__ float Ws[64 * DOUT];
  __shared__ float xs[16 * 128];
  __shared__ float s4[4];
  const int t = threadIdx.x;
  // ---- softmax statistics prologue (identical in every block) ----
  float mloc = -3.0e38f;
  for (int k = t; k < n; k += 256) mloc = fmaxf(mloc, En[k]);
  const float m = blkred(mloc, true, s4);
  const float invden = -1.0f / ((m + 1e-12f) * TEMP_);   // li = En*invden
  float se = 0.f, sl = 0.f;
  for (int k = t; k < n; k += 256) {
    float li = En[k] * invden;
    float e = __expf(li);
    se += e; sl += e * li;
  }
  se = blkred(se, false, s4);
  sl = blkred(sl, false, s4);
  const float logZ = __logf(se);
  const float S = logZ - sl / se;
  const float cmul = (1.0f / se) * (1.0f / TEMP_);
  const float cadd = S - logZ;

  // ---- per-node combine + LN ----
  const int lane = t & 15;
  const int i = blockIdx.x * 16 + (t >> 4);
  const uint4* Gv = (const uint4*)Gb;
  const float4 g0 = ((const float4*)G)[i * 32 + lane * 2];
  const float4 g1 = ((const float4*)G)[i * 32 + lane * 2 + 1];
  const float gi[8] = { g0.x, g0.y, g0.z, g0.w, g1.x, g1.y, g1.z, g1.w };
  float tf[8];
  #pragma unroll
  for (int k = 0; k < 8; ++k) tf[k] = 0.f;
  float atc = 0.f;
  int o = off_d[i];
  const int oe = off_d[i + 1];
  for (; o + 8 <= oe; o += 8) {
    int s[8]; float ev[8]; uint4 r[8];
    #pragma unroll
    for (int j = 0; j < 8; ++j) s[j] = idx_d[o + j];
    #pragma unroll
    for (int j = 0; j < 8; ++j) { r[j] = Gv[s[j] * 16 + lane]; ev[j] = En[s[j]]; }
    #pragma unroll
    for (int j = 0; j < 8; ++j) {
      float ls = ev[j] * invden;
      float cs = __expf(ls) * cmul * (ls + cadd);
      atc += cs;
      float t8[8]; dec8(r[j], t8);
      #pragma unroll
      for (int k = 0; k < 8; ++k) tf[k] = fmaf(cs, t8[k], tf[k]);
    }
  }
  for (; o < oe; ++o) {
    int s = idx_d[o];
    float ls = En[s] * invden;
    float cs = __expf(ls) * cmul * (ls + cadd);
    atc += cs;
    float t8[8]; dec8(Gv[s * 16 + lane], t8);
    #pragma unroll
    for (int k = 0; k < 8; ++k) tf[k] = fmaf(cs, t8[k], tf[k]);
  }
  const float li_i = En[i] * invden;
  const float ci = __expf(li_i) * cmul * (li_i + cadd);
  const float dg = dego[i];
  const float4 a0 = ((const float4*)Ax)[i * 32 + lane * 2];
  const float4 a1 = ((const float4*)Ax)[i * 32 + lane * 2 + 1];
  const float axi[8] = { a0.x, a0.y, a0.z, a0.w, a1.x, a1.y, a1.z, a1.w };
  float v[8];
  float ssum = 0.f;
  #pragma unroll
  for (int k = 0; k < 8; ++k) {
    v[k] = fmaxf(gi[k] + ci * (dg * gi[k] - axi[k]) + atc * gi[k] - tf[k], 0.f);
    ssum += v[k];
  }
  float mu = grp_sum16(ssum) * (1.f / 128.f);
  float vsum = 0.f;
  #pragma unroll
  for (int k = 0; k < 8; ++k) {
    v[k] -= mu;
    vsum += v[k] * v[k];
  }
  float var = grp_sum16(vsum) * (1.f / 128.f);
  float rs = rsqrtf(var + LN_EPS_);
  const float4 ga0 = ((const float4*)gamma)[lane * 2];
  const float4 ga1 = ((const float4*)gamma)[lane * 2 + 1];
  const float4 be0 = ((const float4*)beta)[lane * 2];
  const float4 be1 = ((const float4*)beta)[lane * 2 + 1];
  float4 o0, o1;
  o0.x = fmaf(v[0] * rs, ga0.x, be0.x); o0.y = fmaf(v[1] * rs, ga0.y, be0.y);
  o0.z = fmaf(v[2] * rs, ga0.z, be0.z); o0.w = fmaf(v[3] * rs, ga0.w, be0.w);
  o1.x = fmaf(v[4] * rs, ga1.x, be1.x); o1.y = fmaf(v[5] * rs, ga1.y, be1.y);
  o1.z = fmaf(v[6] * rs, ga1.z, be1.z); o1.w = fmaf(v[7] * rs, ga1.w, be1.w);

  // ---- stage LN rows to LDS, then GEMM this 16-row tile ----
  float* xrow = xs + (t >> 4) * 128 + lane * 8;
  ((float4*)xrow)[0] = o0;
  ((float4*)xrow)[1] = o1;

  const int row0 = blockIdx.x * 16;
  constexpr int RPT = (16 * DOUT) / 256;
  const int c = t % DOUT;
  const int rg = t / DOUT;
  float acc[RPT];
  #pragma unroll
  for (int r = 0; r < RPT; ++r) acc[r] = 0.f;
  for (int kt = 0; kt < 2; ++kt) {
    if (kt) __syncthreads();
    for (int idx = t; idx < 64 * DOUT; idx += 256) Ws[idx] = W[kt * 64 * DOUT + idx];
    __syncthreads();
    for (int k = 0; k < 64; ++k) {
      float wv = Ws[k * DOUT + c];
      #pragma unroll
      for (int r = 0; r < RPT; ++r)
        acc[r] += xs[(rg * RPT + r) * 128 + kt * 64 + k] * wv;
    }
  }
  #pragma unroll
  for (int r = 0; r < RPT; ++r) {
    const int row = row0 + rg * RPT + r;
    Hb[row * DOUT + c] = f2bf(dinv[row] * acc[r]);   // prescaled output
  }
}

// ------- final conv aggregate (prescaled, DOUT=64): 8 lanes/node -----------
__global__ __launch_bounds__(256) void k_final_agg(const unsigned short* __restrict__ Hb,
                                                   const float* __restrict__ dinv,
                                                   const float* __restrict__ bout,
                                                   const int* __restrict__ off_d,
                                                   const int* __restrict__ idx_d,
                                                   float* __restrict__ out) {
  const int lane = threadIdx.x & 7;
  const int i = blockIdx.x * 32 + (threadIdx.x >> 3);
  const uint4* Hv = (const uint4*)Hb;
  const float di = dinv[i];
  float acc[8];
  dec8(Hv[i * 8 + lane], acc);               // self row (already dinv-scaled)
  int o = off_d[i];
  const int oe = off_d[i + 1];
  for (; o + 8 <= oe; o += 8) {
    int s[8]; uint4 r[8];
    #pragma unroll
    for (int j = 0; j < 8; ++j) s[j] = idx_d[o + j];
    #pragma unroll
    for (int j = 0; j < 8; ++j) r[j] = Hv[s[j] * 8 + lane];
    #pragma unroll
    for (int j = 0; j < 8; ++j) {
      float t8[8]; dec8(r[j], t8);
      #pragma unroll
      for (int k = 0; k < 8; ++k) acc[k] += t8[k];
    }
  }
  for (; o < oe; ++o) {
    int s = idx_d[o];
    float t8[8]; dec8(Hv[s * 8 + lane], t8);
    #pragma unroll
    for (int k = 0; k < 8; ++k) acc[k] += t8[k];
  }
  const float4 b0 = ((const float4*)bout)[lane * 2];
  const float4 b1 = ((const float4*)bout)[lane * 2 + 1];
  float4 r0, r1;
  r0.x = fmaf(di, acc[0], b0.x); r0.y = fmaf(di, acc[1], b0.y);
  r0.z = fmaf(di, acc[2], b0.z); r0.w = fmaf(di, acc[3], b0.w);
  r1.x = fmaf(di, acc[4], b1.x); r1.y = fmaf(di, acc[5], b1.y);
  r1.z = fmaf(di, acc[6], b1.z); r1.w = fmaf(di, acc[7], b1.w);
  ((float4*)out)[i * 16 + lane * 2]     = r0;
  ((float4*)out)[i * 16 + lane * 2 + 1] = r1;
}

extern "C" void kernel_launch(void* const* d_in, const int* in_sizes, int n_in,
                              void* d_out, int out_size, void* d_ws, size_t ws_size,
                              hipStream_t stream) {
  const float* x    = (const float*)d_in[0];
  const int*   ei   = (const int*)d_in[1];
  const float* W1   = (const float*)d_in[2];
  const float* b1   = (const float*)d_in[3];
  const float* W2   = (const float*)d_in[4];
  const float* b2   = (const float*)d_in[5];
  const float* Wout = (const float*)d_in[6];
  const float* bout = (const float*)d_in[7];
  const float* gam  = (const float*)d_in[8];
  const float* bet  = (const float*)d_in[9];
  float* out = (float*)d_out;

  const int N = in_sizes[0] / DH;   // 8000
  const int E = in_sizes[1] / 2;    // 256000

  float* ws = (float*)d_ws;
  float* G  = ws;   ws += N * DH;
  float* Ax = ws;   ws += N * DH;
  float* sq = ws;   ws += N;
  float* En = ws;   ws += N;
  float* dinv = ws; ws += N;
  float* dego = ws; ws += N;
  unsigned short* Hb = (unsigned short*)ws; ws += N * DH / 2;   // bf16 N x 128
  unsigned short* Gb = (unsigned short*)ws; ws += N * DH / 2;   // bf16 N x 128
  int* cnt_d  = (int*)ws; ws += N;
  int* cnt_s  = (int*)ws; ws += N;
  int* off_d  = (int*)ws; ws += N + 4;
  int* off_s  = (int*)ws; ws += N + 4;
  int* bsum   = (int*)ws; ws += 64;
  int* idx_d  = (int*)ws; ws += E;
  int* idx_s  = (int*)ws; ws += E;

  const int NT = N / 16;            // 500 gemm tile blocks

  hipMemsetAsync(cnt_d, 0, 2 * N * sizeof(int), stream);  // cnt_d, cnt_s
  k_hist<<<256, 256, 0, stream>>>(ei, E, cnt_d, cnt_s);
  k_scan_a<<<64, 256, 0, stream>>>(cnt_d, cnt_s, off_d, off_s, bsum, dinv, dego, N);
  k_scan_b<<<64, 256, 0, stream>>>(cnt_d, cnt_s, off_d, off_s, bsum, N);
  k_gemm1_fill<<<NT + (E + 255) / 256, 256, 0, stream>>>(x, W1, dinv, Hb, ei, E,
                                                         off_d, off_s, cnt_d, cnt_s,
                                                         idx_d, idx_s, NT);

  // layer 0
  k_conv_agg<<<N / 16, 256, 0, stream>>>(Hb, dinv, b1, off_d, idx_d, G, Gb, sq);
  k_ax_en<<<N / 16, 256, 0, stream>>>(G, Gb, sq, dego, off_s, idx_s, Ax, En);
  k_combine_gemm<128><<<N / 16, 256, 0, stream>>>(G, Gb, Ax, En, dego, dinv, off_d,
                                                  idx_d, gam, bet, W2, Hb, N);
  // layer 1
  k_conv_agg<<<N / 16, 256, 0, stream>>>(Hb, dinv, b2, off_d, idx_d, G, Gb, sq);
  k_ax_en<<<N / 16, 256, 0, stream>>>(G, Gb, sq, dego, off_s, idx_s, Ax, En);
  k_combine_gemm<64><<<N / 16, 256, 0, stream>>>(G, Gb, Ax, En, dego, dinv, off_d,
                                                 idx_d, gam, bet, Wout, Hb, N);
  k_final_agg<<<N / 32, 256, 0, stream>>>(Hb, dinv, bout, off_d, idx_d, out);
}